// Round 12
// baseline (296.919 us; speedup 1.0000x reference)
//
#include <hip/hip_runtime.h>

// Problem constants (reference: B,S,M,D,NQ = 128,100,50,128,10000)
#define BB 128
#define SS 100
#define MM 50
#define DD 128
#define KROW 66                        // key row stride (u32 words), no overlap

typedef float f32x2 __attribute__((ext_vector_type(2)));

#if defined(__has_builtin)
#  if __has_builtin(__builtin_elementwise_fma)
#    define HAVE_PKFMA 1
#  endif
#  if __has_builtin(__builtin_amdgcn_update_dpp)
#    define HAVE_DPP 1
#  endif
#endif

__device__ __forceinline__ f32x2 pkfma(f32x2 a, f32x2 b, f32x2 c) {
#ifdef HAVE_PKFMA
    return __builtin_elementwise_fma(a, b, c);
#else
    f32x2 r; r.x = fmaf(a.x, b.x, c.x); r.y = fmaf(a.y, b.y, c.y); return r;
#endif
}

// quad butterfly add: after xor1+xor2 all 4 lanes of a quad hold the quad sum
__device__ __forceinline__ float qbf_add(float x) {
#ifdef HAVE_DPP
    union { float f; int i; } c, o;
    c.f = x;
    o.i = __builtin_amdgcn_update_dpp(0, c.i, 0xB1, 0xF, 0xF, true);  // quad_perm(1,0,3,2)
    x += o.f;
    c.f = x;
    o.i = __builtin_amdgcn_update_dpp(0, c.i, 0x4E, 0xF, 0xF, true);  // quad_perm(2,3,0,1)
    return x + o.f;
#else
    x += __shfl_xor(x, 1);
    x += __shfl_xor(x, 2);
    return x;
#endif
}

// ---- bf16 helpers ----
__device__ __forceinline__ float bf2f(unsigned short u) {
    union { unsigned int i; float f; } c; c.i = ((unsigned int)u) << 16; return c.f;
}
__device__ __forceinline__ float bfu_lo(unsigned int u) {
    union { unsigned int i; float f; } c; c.i = u << 16; return c.f;
}
__device__ __forceinline__ float bfu_hi(unsigned int u) {
    union { unsigned int i; float f; } c; c.i = u & 0xffff0000u; return c.f;
}
__device__ __forceinline__ unsigned short f2bf_bits(float f) {   // RNE
    union { float f; unsigned int u; } c; c.f = f;
    unsigned int r = (c.u + 0x7FFFu + ((c.u >> 16) & 1u)) >> 16;
    return (unsigned short)r;
}
__device__ __forceinline__ unsigned int packbf(float lo, float hi) {
    return (unsigned int)f2bf_bits(lo) | ((unsigned int)f2bf_bits(hi) << 16);
}
__device__ __forceinline__ float fast_sigmoid(float x) { return 1.0f / (1.0f + __expf(-x)); }
__device__ __forceinline__ float fast_tanh(float x) {
    float ax = fabsf(x);
    float z = __expf(-2.0f * ax);
    float r = (1.0f - z) / (1.0f + z);
    return copysignf(r, x);
}

template <bool BF16>
__device__ __forceinline__ float ldw(const void* p, size_t idx) {
    if (BF16) return bf2f(((const unsigned short*)p)[idx]);
    return ((const float*)p)[idx];
}

#define W2ROW(r) ((r) * 68 + (((r) >> 5) << 3))  // w2 staging rows (build phase)

struct __align__(16) SmemT {
    union {
        struct {                          // staging phase
            unsigned int key_w[MM * KROW];    // 13200 B
            unsigned int qe8[8][68];          // 2176 B
        } pre;                            // 15376 B
        struct {                          // scan phase (fits in pre region)
            unsigned int xread_p[64];         // bf16-packed read: word w = (x_2w, x_2w+1)
            unsigned int xh_p[64];            // bf16-packed h
            float h1f[DD];
        } run;                            // 1024 B
    } u;
    union {
        unsigned int w2s[8724];           // 34896 B (build phase)
        struct {                          // table phase
            unsigned int wrow_p[SS][32];      // word q*8+p = packbf(w[8p+q], w[8p+4+q])
            unsigned short qp_all[SS][DD];
        } tab;
    } v2;                                 // 38400 B
    int qrow[SS];                         // 400 B
    float qlast[DD];                      // 512 B
};                                        // < 64 KB

// 512 threads: wave wv=t>>6, lane l=t&63; q = l&3 (k-quarter), d = wv*16 + (l>>2).
// Quad = 4 lanes of one d -> cross-q reduce = DPP butterfly; d-partner (d^1) = lane l^4.
// v2[p] holds (v[m=8p+q][d], v[m=8p+4+q][d]) as f32x2, p<7 (m>=50 inert: wrow==0).
template <bool BF16>
__device__ void dkvmn_impl(
    const int* __restrict__ qseq,
    const void* emb, const void* key,
    const void* vu_w1, const void* vu_b1, const void* vu_w2, const void* vu_b2,
    const void* er_w, const void* er_b, const void* ad_w, const void* ad_b,
    const void* out_w1, const void* out_b1, const void* out_w2, const void* out_b2,
    void* outp, SmemT& sm)
{
    const int t = threadIdx.x;
    const int b = blockIdx.x;
    const int l = t & 63;
    const int wv = t >> 6;
    const int q = l & 3;
    const int d = (wv << 4) + (l >> 2);

    // ---- stage key (stride 66), w2 (swizzled rows), qrow ----
    if (BF16) {
        const unsigned int* kg = (const unsigned int*)key;
        for (int g = t; g < MM * 64; g += 512)
            sm.u.pre.key_w[(g >> 6) * KROW + (g & 63)] = kg[g];
        const unsigned int* wg = (const unsigned int*)vu_w2;
        for (int g = t; g < 128 * 64; g += 512)
            sm.v2.w2s[W2ROW(g >> 6) + (g & 63)] = wg[g];
    } else {
        const float* kf = (const float*)key;
        for (int g = t; g < MM * 64; g += 512) {
            int row = g >> 6, c2 = g & 63;
            sm.u.pre.key_w[row * KROW + c2] = packbf(kf[row * 128 + 2 * c2], kf[row * 128 + 2 * c2 + 1]);
        }
        const float* wf = (const float*)vu_w2;
        for (int g = t; g < 128 * 64; g += 512) {
            int row = g >> 6, c2 = g & 63;
            sm.v2.w2s[W2ROW(row) + c2] = packbf(wf[row * 128 + 2 * c2], wf[row * 128 + 2 * c2 + 1]);
        }
    }
    for (int g = t; g < SS; g += 512) sm.qrow[g] = qseq[b * SS + g];
    __syncthreads();

    // ---- build fused interleaved columns: rw2ea[k] = ((w2@er)[32q+k][d], (w2@ad)[32q+k][d]) ----
    f32x2 rw2ea[32];
#pragma unroll
    for (int k = 0; k < 32; ++k) { rw2ea[k].x = 0.f; rw2ea[k].y = 0.f; }
    f32x2 eab2; eab2.x = 0.f; eab2.y = 0.f;
#pragma unroll 1
    for (int jc = 0; jc < 4; ++jc) {
        f32x2 ea[32];
#pragma unroll
        for (int i = 0; i < 32; ++i) {
            int j = 32 * jc + i;
            ea[i].x = ldw<BF16>(er_w, (size_t)j * DD + d);
            ea[i].y = ldw<BF16>(ad_w, (size_t)j * DD + d);
            float b2j = ldw<BF16>(vu_b2, j);
            f32x2 bs; bs.x = b2j; bs.y = b2j;
            eab2 = pkfma(bs, ea[i], eab2);
        }
#pragma unroll
        for (int k = 0; k < 32; ++k) {
            const uint4* wp = (const uint4*)&sm.v2.w2s[W2ROW(32 * q + k) + 16 * jc];
            uint4 A = wp[0], B = wp[1], C = wp[2], Dv = wp[3];
            unsigned int W[16] = { A.x, A.y, A.z, A.w, B.x, B.y, B.z, B.w,
                                   C.x, C.y, C.z, C.w, Dv.x, Dv.y, Dv.z, Dv.w };
            f32x2 acc = rw2ea[k];
#pragma unroll
            for (int wd = 0; wd < 16; ++wd) {
                float wlo = bfu_lo(W[wd]), whi = bfu_hi(W[wd]);
                f32x2 s0; s0.x = wlo; s0.y = wlo;
                f32x2 s1; s1.x = whi; s1.y = whi;
                acc = pkfma(s0, ea[2 * wd], acc);
                acc = pkfma(s1, ea[2 * wd + 1], acc);
            }
            rw2ea[k] = acc;
        }
    }
    eab2.x += ldw<BF16>(er_b, d);
    eab2.y += ldw<BF16>(ad_b, d);
    __syncthreads();   // w2s consumed -> v2 region becomes tab

    // ---- w1 columns into registers ----
    float rw1a[32], rw1b[32];
#pragma unroll
    for (int i = 0; i < 32; ++i) {
        rw1a[i] = ldw<BF16>(vu_w1, (size_t)(32 * q + i) * DD + d);
        rw1b[i] = ldw<BF16>(vu_w1, (size_t)(DD + 32 * q + i) * DD + d);
    }
    const float b1r = ldw<BF16>(vu_b1, d);

    // ================= PRECOMPUTE: softmax rows + qe-projections =================
    for (int ii = 0; ii < 13; ++ii) {
        const int nrows = (ii == 12) ? 4 : 8;
        {
            int r = t >> 6, w = t & 63;
            if (r < nrows) {
                int row = sm.qrow[8 * ii + r];
                if (BF16) {
                    sm.u.pre.qe8[r][w] = ((const unsigned int*)emb)[((size_t)row << 6) + w];
                } else {
                    const float* ef = (const float*)emb + (((size_t)row) << 7) + 2 * w;
                    sm.u.pre.qe8[r][w] = packbf(ef[0], ef[1]);
                }
            }
        }
        __syncthreads();

        // logits + softmax: wave wv handles s = 8*ii + wv (lane m = l)
        if (wv < nrows) {
            int m = l;
            int mc = (m < MM) ? m : (MM - 1);
            const uint4* qq = (const uint4*)&sm.u.pre.qe8[wv][0];
            float a0 = 0.f, a1 = 0.f, a2 = 0.f, a3 = 0.f;
#pragma unroll
            for (int j4 = 0; j4 < 16; ++j4) {
                uint4 qwv = qq[j4];
                uint2 kw0 = *(const uint2*)&sm.u.pre.key_w[mc * KROW + 4 * j4];
                uint2 kw1 = *(const uint2*)&sm.u.pre.key_w[mc * KROW + 4 * j4 + 2];
                a0 = fmaf(bfu_lo(kw0.x), bfu_lo(qwv.x), a0);
                a1 = fmaf(bfu_hi(kw0.x), bfu_hi(qwv.x), a1);
                a2 = fmaf(bfu_lo(kw0.y), bfu_lo(qwv.y), a2);
                a3 = fmaf(bfu_hi(kw0.y), bfu_hi(qwv.y), a3);
                a0 = fmaf(bfu_lo(kw1.x), bfu_lo(qwv.z), a0);
                a1 = fmaf(bfu_hi(kw1.x), bfu_hi(qwv.z), a1);
                a2 = fmaf(bfu_lo(kw1.y), bfu_lo(qwv.w), a2);
                a3 = fmaf(bfu_hi(kw1.y), bfu_hi(qwv.w), a3);
            }
            float lg = (a0 + a1) + (a2 + a3);
            if (m >= MM) lg = -1e30f;
            float mx = lg;
#pragma unroll
            for (int o = 32; o > 0; o >>= 1) mx = fmaxf(mx, __shfl_xor(mx, o));
            float p = (m < MM) ? __expf(lg - mx) : 0.f;
            float sum = p;
#pragma unroll
            for (int o = 32; o > 0; o >>= 1) sum += __shfl_xor(sum, o);
            p = p / sum;                       // zeros for m in [50,64)
            float pn = __shfl_xor(p, 4);       // partner m^4
            if ((m & 4) == 0)
                sm.v2.tab.wrow_p[8 * ii + wv][(m & 3) * 8 + (m >> 3)] = packbf(p, pn);
        }

        // qe-projection: thread (d,q), k in [32q, 32q+32); quad butterfly reduce
        for (int sr = 0; sr < nrows; ++sr) {
            const uint4* qq = (const uint4*)&sm.u.pre.qe8[sr][16 * q];
            uint4 Q0 = qq[0], Q1 = qq[1], Q2 = qq[2], Q3 = qq[3];
            unsigned int W[16] = { Q0.x, Q0.y, Q0.z, Q0.w, Q1.x, Q1.y, Q1.z, Q1.w,
                                   Q2.x, Q2.y, Q2.z, Q2.w, Q3.x, Q3.y, Q3.z, Q3.w };
            float p0 = 0.f, p1 = 0.f;
#pragma unroll
            for (int i = 0; i < 16; ++i) {
                p0 = fmaf(rw1b[2 * i],     bfu_lo(W[i]), p0);
                p1 = fmaf(rw1b[2 * i + 1], bfu_hi(W[i]), p1);
            }
            float qpv = qbf_add(p0 + p1);
            if (q == 0) sm.v2.tab.qp_all[8 * ii + sr][d] = f2bf_bits(qpv);
        }
        __syncthreads();
    }

    // save last qe (s=99 lives in qe8[3]); init scan state
    if (t < 64) {
        unsigned int uw = sm.u.pre.qe8[3][t];
        sm.qlast[2 * t]     = bfu_lo(uw);
        sm.qlast[2 * t + 1] = bfu_hi(uw);
    }
    f32x2 v2[7];
#pragma unroll
    for (int p = 0; p < 7; ++p) { v2[p].x = 0.f; v2[p].y = 0.f; }
    f32x2 wr2[7];
    {
        const uint4* wp = (const uint4*)&sm.v2.tab.wrow_p[0][q * 8];
        uint4 w0 = wp[0], w1 = wp[1];
        unsigned int ww[8] = { w0.x, w0.y, w0.z, w0.w, w1.x, w1.y, w1.z, w1.w };
#pragma unroll
        for (int p = 0; p < 7; ++p) { wr2[p].x = bfu_lo(ww[p]); wr2[p].y = bfu_hi(ww[p]); }
    }
    if (t < 64) sm.u.run.xread_p[t] = 0;   // read0 = 0 (v0 = 0); bf16 zeros
    __syncthreads();

    // ================= SCAN: 2 barriers per step =================
    for (int s = 0; s < SS; ++s) {
        // ---- E: h = tanh(read @ w1a + qp + b1); bf16-packed stage IO ----
        {
            float qpv = bf2f(sm.v2.tab.qp_all[s][d]);
            const uint4* xp = (const uint4*)&sm.u.run.xread_p[16 * q];
            uint4 X0 = xp[0], X1 = xp[1], X2 = xp[2], X3 = xp[3];
            unsigned int W[16] = { X0.x, X0.y, X0.z, X0.w, X1.x, X1.y, X1.z, X1.w,
                                   X2.x, X2.y, X2.z, X2.w, X3.x, X3.y, X3.z, X3.w };
            float a0 = 0.f, a1 = 0.f, a2 = 0.f, a3 = 0.f;
#pragma unroll
            for (int i = 0; i < 8; ++i) {
                a0 = fmaf(rw1a[2 * i],      bfu_lo(W[i]), a0);
                a1 = fmaf(rw1a[2 * i + 1],  bfu_hi(W[i]), a1);
                a2 = fmaf(rw1a[2 * i + 16], bfu_lo(W[i + 8]), a2);
                a3 = fmaf(rw1a[2 * i + 17], bfu_hi(W[i + 8]), a3);
            }
            float acc = qbf_add((a0 + a1) + (a2 + a3));
            float hh = fast_tanh(acc + qpv + b1r);
            float hp = __shfl_xor(hh, 4);      // d-partner's h
            if (q == 0 && !(d & 1))
                sm.u.run.xh_p[d >> 1] = packbf(hh, hp);
        }
        __syncthreads();

        // ---- G: (e,a) via interleaved pk matvec on packed h; v-update; next read ----
        {
            const uint4* xp = (const uint4*)&sm.u.run.xh_p[16 * q];
            uint4 X0 = xp[0], X1 = xp[1], X2 = xp[2], X3 = xp[3];
            unsigned int W[16] = { X0.x, X0.y, X0.z, X0.w, X1.x, X1.y, X1.z, X1.w,
                                   X2.x, X2.y, X2.z, X2.w, X3.x, X3.y, X3.z, X3.w };
            f32x2 acc2; acc2.x = 0.f; acc2.y = 0.f;
#pragma unroll
            for (int i = 0; i < 16; ++i) {
                float lo = bfu_lo(W[i]), hi = bfu_hi(W[i]);
                f32x2 s0; s0.x = lo; s0.y = lo;
                f32x2 s1; s1.x = hi; s1.y = hi;
                acc2 = pkfma(rw2ea[2 * i], s0, acc2);
                acc2 = pkfma(rw2ea[2 * i + 1], s1, acc2);
            }
            float ae = qbf_add(acc2.x);
            float aa = qbf_add(acc2.y);
            float e = fast_sigmoid(ae + eab2.x);
            float a = fast_tanh(aa + eab2.y);
            f32x2 me; me.x = -e; me.y = -e;
            f32x2 av; av.x = a;  av.y = a;
#pragma unroll
            for (int p = 0; p < 7; ++p)
                v2[p] = pkfma(wr2[p], pkfma(me, v2[p], av), v2[p]);
            if (s + 1 < SS) {   // advance wrow; at s=99 keep wrow[99] for the final read
                const uint4* wp = (const uint4*)&sm.v2.tab.wrow_p[s + 1][q * 8];
                uint4 w0 = wp[0], w1 = wp[1];
                unsigned int ww[8] = { w0.x, w0.y, w0.z, w0.w, w1.x, w1.y, w1.z, w1.w };
#pragma unroll
                for (int p = 0; p < 7; ++p) { wr2[p].x = bfu_lo(ww[p]); wr2[p].y = bfu_hi(ww[p]); }
            }
            f32x2 racc; racc.x = 0.f; racc.y = 0.f;
#pragma unroll
            for (int p = 0; p < 7; ++p)
                racc = pkfma(wr2[p], v2[p], racc);
            float rr = qbf_add(racc.x + racc.y);
            float rp = __shfl_xor(rr, 4);      // d-partner's read
            if (q == 0 && !(d & 1))
                sm.u.run.xread_p[d >> 1] = packbf(rr, rp);
        }
        __syncthreads();
    }

    // ---- Epilogue: xread_p holds final read (bf16-packed); qlast holds qe[99] ----
    float acc = 0.f;
    {
        const uint4* xp = (const uint4*)&sm.u.run.xread_p[16 * q];
        uint4 X0 = xp[0], X1 = xp[1], X2 = xp[2], X3 = xp[3];
        unsigned int W[16] = { X0.x, X0.y, X0.z, X0.w, X1.x, X1.y, X1.z, X1.w,
                               X2.x, X2.y, X2.z, X2.w, X3.x, X3.y, X3.z, X3.w };
#pragma unroll
        for (int i = 0; i < 16; ++i) {
            int k = 32 * q + 2 * i;
            acc = fmaf(ldw<BF16>(out_w1, (size_t)k * DD + d),       bfu_lo(W[i]), acc);
            acc = fmaf(ldw<BF16>(out_w1, (size_t)(k + 1) * DD + d), bfu_hi(W[i]), acc);
        }
        const float4* qp4 = (const float4*)&sm.qlast[32 * q];
#pragma unroll
        for (int j = 0; j < 8; ++j) {
            float4 qv = qp4[j];
            int k = DD + 32 * q + 4 * j;
            acc = fmaf(ldw<BF16>(out_w1, (size_t)k * DD + d),       qv.x, acc);
            acc = fmaf(ldw<BF16>(out_w1, (size_t)(k + 1) * DD + d), qv.y, acc);
            acc = fmaf(ldw<BF16>(out_w1, (size_t)(k + 2) * DD + d), qv.z, acc);
            acc = fmaf(ldw<BF16>(out_w1, (size_t)(k + 3) * DD + d), qv.w, acc);
        }
    }
    acc = qbf_add(acc);
    float h1 = fmaxf(acc + ldw<BF16>(out_b1, d), 0.f);
    if (q == 0) sm.u.run.h1f[d] = h1;
    __syncthreads();

    if (t < 64) {
        float xs = fmaf(sm.u.run.h1f[t], ldw<BF16>(out_w2, t),
                        sm.u.run.h1f[64 + t] * ldw<BF16>(out_w2, 64 + t));
#pragma unroll
        for (int o = 32; o > 0; o >>= 1) xs += __shfl_xor(xs, o);
        if (t == 0) {
            float pred = fast_sigmoid(xs + ldw<BF16>(out_b2, 0));
            if (BF16) ((unsigned short*)outp)[b] = f2bf_bits(pred);
            else      ((float*)outp)[b] = pred;
        }
    }
}

__global__ __launch_bounds__(512) void DKVMN_78546361909953_kernel(
    const int* __restrict__ qseq,
    const void* emb, const void* key,
    const void* vu_w1, const void* vu_b1, const void* vu_w2, const void* vu_b2,
    const void* er_w, const void* er_b, const void* ad_w, const void* ad_b,
    const void* out_w1, const void* out_b1, const void* out_w2, const void* out_b2,
    void* outp)
{
    __shared__ SmemT sm;

    // Runtime storage-dtype detection (proven rounds 5-11: BF16 path taken).
    const unsigned int* eu = (const unsigned int*)emb;
    int cnt = 0;
    for (int i = 0; i < 32; ++i) {
        unsigned int e8 = (eu[i] >> 7) & 0xFFu;
        cnt += (e8 >= 100u && e8 <= 127u) ? 1 : 0;
    }
    if (cnt >= 16)
        dkvmn_impl<true>(qseq, emb, key, vu_w1, vu_b1, vu_w2, vu_b2,
                         er_w, er_b, ad_w, ad_b, out_w1, out_b1, out_w2, out_b2, outp, sm);
    else
        dkvmn_impl<false>(qseq, emb, key, vu_w1, vu_b1, vu_w2, vu_b2,
                          er_w, er_b, ad_w, ad_b, out_w1, out_b1, out_w2, out_b2, outp, sm);
}

extern "C" void kernel_launch(void* const* d_in, const int* in_sizes, int n_in,
                              void* d_out, int out_size, void* d_ws, size_t ws_size,
                              hipStream_t stream) {
    const int* qseq = (const int*)d_in[0];
    // d_in[1] = answer_seq: unused by the reference
    DKVMN_78546361909953_kernel<<<BB, 512, 0, stream>>>(
        qseq,
        d_in[2], d_in[3], d_in[4], d_in[5], d_in[6], d_in[7],
        d_in[8], d_in[9], d_in[10], d_in[11],
        d_in[12], d_in[13], d_in[14], d_in[15],
        d_out);
}

// Round 13
// 259.704 us; speedup vs baseline: 1.1433x; 1.1433x over previous
//
#include <hip/hip_runtime.h>

// Problem constants (reference: B,S,M,D,NQ = 128,100,50,128,10000)
#define BB 128
#define SS 100
#define MM 50
#define DD 128
#define KROW 66                        // key row stride (u32 words), no overlap

typedef float f32x2 __attribute__((ext_vector_type(2)));

#if defined(__has_builtin)
#  if __has_builtin(__builtin_elementwise_fma)
#    define HAVE_PKFMA 1
#  endif
#  if __has_builtin(__builtin_amdgcn_update_dpp)
#    define HAVE_DPP 1
#  endif
#endif

__device__ __forceinline__ f32x2 pkfma(f32x2 a, f32x2 b, f32x2 c) {
#ifdef HAVE_PKFMA
    return __builtin_elementwise_fma(a, b, c);
#else
    f32x2 r; r.x = fmaf(a.x, b.x, c.x); r.y = fmaf(a.y, b.y, c.y); return r;
#endif
}

__device__ __forceinline__ float qbf_add(float x) {
#ifdef HAVE_DPP
    union { float f; int i; } c, o;
    c.f = x;
    o.i = __builtin_amdgcn_update_dpp(0, c.i, 0xB1, 0xF, 0xF, true);  // quad_perm(1,0,3,2)
    x += o.f;
    c.f = x;
    o.i = __builtin_amdgcn_update_dpp(0, c.i, 0x4E, 0xF, 0xF, true);  // quad_perm(2,3,0,1)
    return x + o.f;
#else
    x += __shfl_xor(x, 1);
    x += __shfl_xor(x, 2);
    return x;
#endif
}

// ---- bf16 helpers ----
__device__ __forceinline__ float bf2f(unsigned short u) {
    union { unsigned int i; float f; } c; c.i = ((unsigned int)u) << 16; return c.f;
}
__device__ __forceinline__ float bfu_lo(unsigned int u) {
    union { unsigned int i; float f; } c; c.i = u << 16; return c.f;
}
__device__ __forceinline__ float bfu_hi(unsigned int u) {
    union { unsigned int i; float f; } c; c.i = u & 0xffff0000u; return c.f;
}
__device__ __forceinline__ unsigned short f2bf_bits(float f) {   // RNE
    union { float f; unsigned int u; } c; c.f = f;
    unsigned int r = (c.u + 0x7FFFu + ((c.u >> 16) & 1u)) >> 16;
    return (unsigned short)r;
}
__device__ __forceinline__ unsigned int packbf(float lo, float hi) {
    return (unsigned int)f2bf_bits(lo) | ((unsigned int)f2bf_bits(hi) << 16);
}
__device__ __forceinline__ float fast_sigmoid(float x) { return 1.0f / (1.0f + __expf(-x)); }
__device__ __forceinline__ float fast_tanh(float x) {
    float ax = fabsf(x);
    float z = __expf(-2.0f * ax);
    float r = (1.0f - z) / (1.0f + z);
    return copysignf(r, x);
}

template <bool BF16>
__device__ __forceinline__ float ldw(const void* p, size_t idx) {
    if (BF16) return bf2f(((const unsigned short*)p)[idx]);
    return ((const float*)p)[idx];
}

__device__ __forceinline__ bool detect_bf16(const void* emb) {
    const unsigned int* eu = (const unsigned int*)emb;
    int cnt = 0;
    for (int i = 0; i < 32; ++i) {
        unsigned int e8 = (eu[i] >> 7) & 0xFFu;
        cnt += (e8 >= 100u && e8 <= 127u) ? 1 : 0;
    }
    return cnt >= 16;
}

#define W2ROW(r) ((r) * 68 + (((r) >> 5) << 3))

// ---- workspace layout (bytes) ----
#define WS_WROW_OFF 0u
#define WS_QP_OFF   (BB * SS * 32u * 4u)                 // 1,638,400
#define WS_W2EA_OFF (WS_QP_OFF + BB * SS * DD * 2u)      // 4,915,200
#define WS_EAB_OFF  (WS_W2EA_OFF + DD * DD * 8u)         // 5,046,272
#define WS_NEED     (WS_EAB_OFF + DD * 8u)               // 5,047,296

// =====================================================================
// Kernel A: grid (129, 2) x 512. Blocks (b<128, half): attention softmax +
// qe-projection for s in [50*half, 50*half+50). Block (128,0): W2EA build.
// =====================================================================
struct __align__(16) SmemA {
    union {
        struct {
            unsigned int key_w[MM * KROW];
            unsigned int qe8[8][68];
        } pre;
        unsigned int w2s[8724];
    } u;
};

template <bool BF16>
__device__ void pre_impl(const int* qseq, const void* emb, const void* key,
                         const void* vu_w1, unsigned int* wrow_g, unsigned short* qp_g,
                         SmemA& sm)
{
    const int t = threadIdx.x;
    const int b = blockIdx.x;
    const int half = blockIdx.y;
    const int l = t & 63;
    const int wv = t >> 6;
    const int q = l & 3;
    const int d = (wv << 4) + (l >> 2);

    if (BF16) {
        const unsigned int* kg = (const unsigned int*)key;
        for (int g = t; g < MM * 64; g += 512)
            sm.u.pre.key_w[(g >> 6) * KROW + (g & 63)] = kg[g];
    } else {
        const float* kf = (const float*)key;
        for (int g = t; g < MM * 64; g += 512) {
            int row = g >> 6, c2 = g & 63;
            sm.u.pre.key_w[row * KROW + c2] = packbf(kf[row * 128 + 2 * c2], kf[row * 128 + 2 * c2 + 1]);
        }
    }

    float rw1b[32];
#pragma unroll
    for (int i = 0; i < 32; ++i)
        rw1b[i] = ldw<BF16>(vu_w1, (size_t)(DD + 32 * q + i) * DD + d);
    __syncthreads();

    for (int ii = 0; ii < 7; ++ii) {
        const int nrows = (ii == 6) ? 2 : 8;
        {
            int r = t >> 6, w = t & 63;
            if (r < nrows) {
                int s = 50 * half + 8 * ii + r;
                int row = qseq[b * SS + s];
                if (BF16) {
                    sm.u.pre.qe8[r][w] = ((const unsigned int*)emb)[((size_t)row << 6) + w];
                } else {
                    const float* ef = (const float*)emb + (((size_t)row) << 7) + 2 * w;
                    sm.u.pre.qe8[r][w] = packbf(ef[0], ef[1]);
                }
            }
        }
        __syncthreads();

        if (wv < nrows) {
            int m = l;
            int mc = (m < MM) ? m : (MM - 1);
            float a0 = 0.f, a1 = 0.f, a2 = 0.f, a3 = 0.f;
#pragma unroll
            for (int j = 0; j < 32; ++j) {
                uint2 kw = *(const uint2*)&sm.u.pre.key_w[mc * KROW + 2 * j];
                uint2 qw = *(const uint2*)&sm.u.pre.qe8[wv][2 * j];
                a0 = fmaf(bfu_lo(kw.x), bfu_lo(qw.x), a0);
                a1 = fmaf(bfu_hi(kw.x), bfu_hi(qw.x), a1);
                a2 = fmaf(bfu_lo(kw.y), bfu_lo(qw.y), a2);
                a3 = fmaf(bfu_hi(kw.y), bfu_hi(qw.y), a3);
            }
            float lg = (a0 + a1) + (a2 + a3);
            if (m >= MM) lg = -1e30f;
            float mx = lg;
#pragma unroll
            for (int o = 32; o > 0; o >>= 1) mx = fmaxf(mx, __shfl_xor(mx, o));
            float p = (m < MM) ? __expf(lg - mx) : 0.f;
            float sum = p;
#pragma unroll
            for (int o = 32; o > 0; o >>= 1) sum += __shfl_xor(sum, o);
            p = p / sum;
            float pn = __shfl_xor(p, 4);
            int s = 50 * half + 8 * ii + wv;
            if ((m & 4) == 0)
                wrow_g[(size_t)(b * SS + s) * 32 + (m & 3) * 8 + (m >> 3)] = packbf(p, pn);
        }

        for (int sr = 0; sr < nrows; ++sr) {
            float p0 = 0.f, p1 = 0.f;
#pragma unroll
            for (int i = 0; i < 16; ++i) {
                unsigned int uw = sm.u.pre.qe8[sr][16 * q + i];
                p0 = fmaf(rw1b[2 * i],     bfu_lo(uw), p0);
                p1 = fmaf(rw1b[2 * i + 1], bfu_hi(uw), p1);
            }
            float qpv = qbf_add(p0 + p1);
            int s = 50 * half + 8 * ii + sr;
            if (q == 0) qp_g[(size_t)(b * SS + s) * DD + d] = f2bf_bits(qpv);
        }
        __syncthreads();
    }
}

template <bool BF16>
__device__ void build_impl(const void* vu_w2, const void* vu_b2,
                           const void* er_w, const void* er_b,
                           const void* ad_w, const void* ad_b,
                           f32x2* w2ea_g, f32x2* eab_g, SmemA& sm)
{
    const int t = threadIdx.x;
    const int l = t & 63;
    const int wv = t >> 6;
    const int q = l & 3;
    const int d = (wv << 4) + (l >> 2);

    if (BF16) {
        const unsigned int* wg = (const unsigned int*)vu_w2;
        for (int g = t; g < 128 * 64; g += 512)
            sm.u.w2s[W2ROW(g >> 6) + (g & 63)] = wg[g];
    } else {
        const float* wf = (const float*)vu_w2;
        for (int g = t; g < 128 * 64; g += 512) {
            int row = g >> 6, c2 = g & 63;
            sm.u.w2s[W2ROW(row) + c2] = packbf(wf[row * 128 + 2 * c2], wf[row * 128 + 2 * c2 + 1]);
        }
    }
    __syncthreads();

    f32x2 rw2ea[32];
#pragma unroll
    for (int k = 0; k < 32; ++k) { rw2ea[k].x = 0.f; rw2ea[k].y = 0.f; }
    f32x2 eab2; eab2.x = 0.f; eab2.y = 0.f;
#pragma unroll 1
    for (int jc = 0; jc < 4; ++jc) {
        f32x2 ea[32];
#pragma unroll
        for (int i = 0; i < 32; ++i) {
            int j = 32 * jc + i;
            ea[i].x = ldw<BF16>(er_w, (size_t)j * DD + d);
            ea[i].y = ldw<BF16>(ad_w, (size_t)j * DD + d);
            float b2j = ldw<BF16>(vu_b2, j);
            f32x2 bs; bs.x = b2j; bs.y = b2j;
            eab2 = pkfma(bs, ea[i], eab2);
        }
#pragma unroll
        for (int k = 0; k < 32; ++k) {
            const uint4* wp = (const uint4*)&sm.u.w2s[W2ROW(32 * q + k) + 16 * jc];
            uint4 A = wp[0], B = wp[1], C = wp[2], Dv = wp[3];
            unsigned int W[16] = { A.x, A.y, A.z, A.w, B.x, B.y, B.z, B.w,
                                   C.x, C.y, C.z, C.w, Dv.x, Dv.y, Dv.z, Dv.w };
            f32x2 acc = rw2ea[k];
#pragma unroll
            for (int wd = 0; wd < 16; ++wd) {
                float wlo = bfu_lo(W[wd]), whi = bfu_hi(W[wd]);
                f32x2 s0; s0.x = wlo; s0.y = wlo;
                f32x2 s1; s1.x = whi; s1.y = whi;
                acc = pkfma(s0, ea[2 * wd], acc);
                acc = pkfma(s1, ea[2 * wd + 1], acc);
            }
            rw2ea[k] = acc;
        }
    }
    eab2.x += ldw<BF16>(er_b, d);
    eab2.y += ldw<BF16>(ad_b, d);

#pragma unroll
    for (int k = 0; k < 32; ++k)
        w2ea_g[(size_t)(32 * q + k) * DD + d] = rw2ea[k];
    if (q == 0) eab_g[d] = eab2;
}

__global__ __launch_bounds__(512) void DKVMN_78546361909953_pre(
    const int* __restrict__ qseq,
    const void* emb, const void* key, const void* vu_w1,
    const void* vu_w2, const void* vu_b2,
    const void* er_w, const void* er_b, const void* ad_w, const void* ad_b,
    void* ws)
{
    __shared__ SmemA sm;
    unsigned int*   wrow_g = (unsigned int*)((char*)ws + WS_WROW_OFF);
    unsigned short* qp_g   = (unsigned short*)((char*)ws + WS_QP_OFF);
    f32x2*          w2ea_g = (f32x2*)((char*)ws + WS_W2EA_OFF);
    f32x2*          eab_g  = (f32x2*)((char*)ws + WS_EAB_OFF);
    bool isbf = detect_bf16(emb);
    if (blockIdx.x < BB) {
        if (isbf) pre_impl<true>(qseq, emb, key, vu_w1, wrow_g, qp_g, sm);
        else      pre_impl<false>(qseq, emb, key, vu_w1, wrow_g, qp_g, sm);
    } else if (blockIdx.y == 0) {
        if (isbf) build_impl<true>(vu_w2, vu_b2, er_w, er_b, ad_w, ad_b, w2ea_g, eab_g, sm);
        else      build_impl<false>(vu_w2, vu_b2, er_w, er_b, ad_w, ad_b, w2ea_g, eab_g, sm);
    }
}

// =====================================================================
// Kernel B: 128 blocks x 512. r11's 2-interval scan; tables from ws
// (wrow/qp prefetched one interval ahead into registers).
// =====================================================================
struct __align__(16) SmemB {
    float xread[152];
    float xhdup[312];
    float h1f[DD];
    float qlast[DD];
};

template <bool BF16>
__device__ void scan_impl(
    const int* __restrict__ qseq,
    const void* emb, const void* vu_w1, const void* vu_b1,
    const void* out_w1, const void* out_b1, const void* out_w2, const void* out_b2,
    const unsigned int* wrow_g, const unsigned short* qp_g,
    const f32x2* w2ea_g, const f32x2* eab_g,
    void* outp, SmemB& sm)
{
    const int t = threadIdx.x;
    const int b = blockIdx.x;
    const int l = t & 63;
    const int q = l & 3;
    const int d = ((t >> 6) << 4) + (l >> 2);

    if (t < 64) {
        int row = qseq[b * SS + (SS - 1)];
        if (BF16) {
            unsigned int uw = ((const unsigned int*)emb)[((size_t)row << 6) + t];
            sm.qlast[2 * t]     = bfu_lo(uw);
            sm.qlast[2 * t + 1] = bfu_hi(uw);
        } else {
            const float* ef = (const float*)emb + (((size_t)row) << 7) + 2 * t;
            sm.qlast[2 * t]     = ef[0];
            sm.qlast[2 * t + 1] = ef[1];
        }
    }

    f32x2 rw1a2[16];
#pragma unroll
    for (int i = 0; i < 16; ++i) {
        int k0 = 32 * q + 2 * i;
        rw1a2[i].x = ldw<BF16>(vu_w1, (size_t)k0 * DD + d);
        rw1a2[i].y = ldw<BF16>(vu_w1, (size_t)(k0 + 1) * DD + d);
    }
    const float b1r = ldw<BF16>(vu_b1, d);

    f32x2 rw2ea[32];
#pragma unroll
    for (int k = 0; k < 32; ++k)
        rw2ea[k] = w2ea_g[(size_t)(32 * q + k) * DD + d];
    const f32x2 eab2 = eab_g[d];

    f32x2 v2[7];
#pragma unroll
    for (int p = 0; p < 7; ++p) { v2[p].x = 0.f; v2[p].y = 0.f; }
    f32x2 wr2[7];
    {
        const size_t r0 = (size_t)(b * SS) * 32 + q * 8;
        uint4 w0 = *(const uint4*)&wrow_g[r0];
        uint4 w1 = *(const uint4*)&wrow_g[r0 + 4];
        unsigned int ww[8] = { w0.x, w0.y, w0.z, w0.w, w1.x, w1.y, w1.z, w1.w };
#pragma unroll
        for (int p = 0; p < 7; ++p) { wr2[p].x = bfu_lo(ww[p]); wr2[p].y = bfu_hi(ww[p]); }
    }
    unsigned short qpcur = qp_g[(size_t)(b * SS) * DD + d];

    if (t < 152) sm.xread[t] = 0.f;
    __syncthreads();

    for (int s = 0; s < SS; ++s) {
        uint4 pwA, pwB;
        unsigned short pq = 0;
        const bool hasnext = (s + 1 < SS);
        if (hasnext) {                               // prefetch s+1 tables (used one interval later)
            size_t r1 = (size_t)(b * SS + s + 1);
            pwA = *(const uint4*)&wrow_g[r1 * 32 + q * 8];
            pwB = *(const uint4*)&wrow_g[r1 * 32 + q * 8 + 4];
            pq  = qp_g[r1 * DD + d];
        }

        // ---- E: h = tanh(read @ w1a + qp + b1) ----
        {
            float qpv = bf2f(qpcur);
            const float4* xp = (const float4*)&sm.xread[40 * q];
            f32x2 acc2; acc2.x = 0.f; acc2.y = 0.f;
#pragma unroll
            for (int j = 0; j < 8; ++j) {
                float4 X = xp[j];
                f32x2 x01; x01.x = X.x; x01.y = X.y;
                f32x2 x23; x23.x = X.z; x23.y = X.w;
                acc2 = pkfma(rw1a2[2 * j], x01, acc2);
                acc2 = pkfma(rw1a2[2 * j + 1], x23, acc2);
            }
            float acc = qbf_add(acc2.x + acc2.y);
            float hh = fast_tanh(acc + qpv + b1r);
            if (q == 0) {
                f32x2 hd; hd.x = hh; hd.y = hh;
                *(f32x2*)&sm.xhdup[2 * d + 8 * ((2 * d) >> 5)] = hd;
            }
        }
        __syncthreads();

        // ---- G: (e,a); v-update; advance wrow (prefetched); next read ----
        {
            f32x2 acc2; acc2.x = 0.f; acc2.y = 0.f;
#pragma unroll
            for (int blk = 0; blk < 2; ++blk) {
                const float4* xp = (const float4*)&sm.xhdup[80 * q + 40 * blk];
#pragma unroll
                for (int j = 0; j < 8; ++j) {
                    float4 X = xp[j];
                    f32x2 s0; s0.x = X.x; s0.y = X.y;
                    f32x2 s1; s1.x = X.z; s1.y = X.w;
                    int k = 16 * blk + 2 * j;
                    acc2 = pkfma(rw2ea[k], s0, acc2);
                    acc2 = pkfma(rw2ea[k + 1], s1, acc2);
                }
            }
            float ae = qbf_add(acc2.x);
            float aa = qbf_add(acc2.y);
            float e = fast_sigmoid(ae + eab2.x);
            float a = fast_tanh(aa + eab2.y);
            f32x2 me; me.x = -e; me.y = -e;
            f32x2 av; av.x = a;  av.y = a;
#pragma unroll
            for (int p = 0; p < 7; ++p)
                v2[p] = pkfma(wr2[p], pkfma(me, v2[p], av), v2[p]);
            if (hasnext) {
                unsigned int ww[8] = { pwA.x, pwA.y, pwA.z, pwA.w, pwB.x, pwB.y, pwB.z, pwB.w };
#pragma unroll
                for (int p = 0; p < 7; ++p) { wr2[p].x = bfu_lo(ww[p]); wr2[p].y = bfu_hi(ww[p]); }
                qpcur = pq;
            }
            f32x2 racc; racc.x = 0.f; racc.y = 0.f;
#pragma unroll
            for (int p = 0; p < 7; ++p)
                racc = pkfma(wr2[p], v2[p], racc);
            float rr = qbf_add(racc.x + racc.y);
            if (q == 0) sm.xread[rr == rr ? (d + 8 * (d >> 5)) : 0] = rr;   // XW(d)
        }
        __syncthreads();
    }

    // ---- Epilogue ----
    float acc = 0.f;
    {
        const float4* xp = (const float4*)&sm.xread[40 * q];
        const float4* qp4 = (const float4*)&sm.qlast[32 * q];
#pragma unroll
        for (int j = 0; j < 8; ++j) {
            float4 xv = xp[j];
            float4 qv = qp4[j];
            int k = 32 * q + 4 * j;
            acc = fmaf(ldw<BF16>(out_w1, (size_t)k * DD + d),       xv.x, acc);
            acc = fmaf(ldw<BF16>(out_w1, (size_t)(k + 1) * DD + d), xv.y, acc);
            acc = fmaf(ldw<BF16>(out_w1, (size_t)(k + 2) * DD + d), xv.z, acc);
            acc = fmaf(ldw<BF16>(out_w1, (size_t)(k + 3) * DD + d), xv.w, acc);
            acc = fmaf(ldw<BF16>(out_w1, (size_t)(DD + k) * DD + d),     qv.x, acc);
            acc = fmaf(ldw<BF16>(out_w1, (size_t)(DD + k + 1) * DD + d), qv.y, acc);
            acc = fmaf(ldw<BF16>(out_w1, (size_t)(DD + k + 2) * DD + d), qv.z, acc);
            acc = fmaf(ldw<BF16>(out_w1, (size_t)(DD + k + 3) * DD + d), qv.w, acc);
        }
    }
    acc = qbf_add(acc);
    float h1 = fmaxf(acc + ldw<BF16>(out_b1, d), 0.f);
    if (q == 0) sm.h1f[d] = h1;
    __syncthreads();

    if (t < 64) {
        float xs = fmaf(sm.h1f[t], ldw<BF16>(out_w2, t),
                        sm.h1f[64 + t] * ldw<BF16>(out_w2, 64 + t));
#pragma unroll
        for (int o = 32; o > 0; o >>= 1) xs += __shfl_xor(xs, o);
        if (t == 0) {
            float pred = fast_sigmoid(xs + ldw<BF16>(out_b2, 0));
            if (BF16) ((unsigned short*)outp)[b] = f2bf_bits(pred);
            else      ((float*)outp)[b] = pred;
        }
    }
}

__global__ __launch_bounds__(512) void DKVMN_78546361909953_scan(
    const int* __restrict__ qseq,
    const void* emb, const void* vu_w1, const void* vu_b1,
    const void* out_w1, const void* out_b1, const void* out_w2, const void* out_b2,
    void* ws, void* outp)
{
    __shared__ SmemB sm;
    const unsigned int*   wrow_g = (const unsigned int*)((char*)ws + WS_WROW_OFF);
    const unsigned short* qp_g   = (const unsigned short*)((char*)ws + WS_QP_OFF);
    const f32x2*          w2ea_g = (const f32x2*)((char*)ws + WS_W2EA_OFF);
    const f32x2*          eab_g  = (const f32x2*)((char*)ws + WS_EAB_OFF);
    if (detect_bf16(emb))
        scan_impl<true>(qseq, emb, vu_w1, vu_b1, out_w1, out_b1, out_w2, out_b2,
                        wrow_g, qp_g, w2ea_g, eab_g, outp, sm);
    else
        scan_impl<false>(qseq, emb, vu_w1, vu_b1, out_w1, out_b1, out_w2, out_b2,
                         wrow_g, qp_g, w2ea_g, eab_g, outp, sm);
}

// =====================================================================
// Monolithic fallback (r11 verbatim) — used when ws_size < WS_NEED.
// =====================================================================
struct __align__(16) SmemM {
    union {
        struct {
            unsigned int key_w[MM * KROW];
            unsigned int qe8[8][68];
        } pre;
        struct {
            float xread[152];
            float xhdup[312];
            float h1f[DD];
        } run;
    } u;
    union {
        unsigned int w2s[8724];
        struct {
            unsigned int wrow_p[SS][32];
            unsigned short qp_all[SS][DD];
        } tab;
    } v2;
    int qrow[SS];
    float qlast[DD];
};

template <bool BF16>
__device__ void mono_impl(
    const int* __restrict__ qseq,
    const void* emb, const void* key,
    const void* vu_w1, const void* vu_b1, const void* vu_w2, const void* vu_b2,
    const void* er_w, const void* er_b, const void* ad_w, const void* ad_b,
    const void* out_w1, const void* out_b1, const void* out_w2, const void* out_b2,
    void* outp, SmemM& sm)
{
    const int t = threadIdx.x;
    const int b = blockIdx.x;
    const int l = t & 63;
    const int wv = t >> 6;
    const int q = l & 3;
    const int d = (wv << 4) + (l >> 2);

    if (BF16) {
        const unsigned int* kg = (const unsigned int*)key;
        for (int g = t; g < MM * 64; g += 512)
            sm.u.pre.key_w[(g >> 6) * KROW + (g & 63)] = kg[g];
        const unsigned int* wg = (const unsigned int*)vu_w2;
        for (int g = t; g < 128 * 64; g += 512)
            sm.v2.w2s[W2ROW(g >> 6) + (g & 63)] = wg[g];
    } else {
        const float* kf = (const float*)key;
        for (int g = t; g < MM * 64; g += 512) {
            int row = g >> 6, c2 = g & 63;
            sm.u.pre.key_w[row * KROW + c2] = packbf(kf[row * 128 + 2 * c2], kf[row * 128 + 2 * c2 + 1]);
        }
        const float* wf = (const float*)vu_w2;
        for (int g = t; g < 128 * 64; g += 512) {
            int row = g >> 6, c2 = g & 63;
            sm.v2.w2s[W2ROW(row) + c2] = packbf(wf[row * 128 + 2 * c2], wf[row * 128 + 2 * c2 + 1]);
        }
    }
    for (int g = t; g < SS; g += 512) sm.qrow[g] = qseq[b * SS + g];
    __syncthreads();

    f32x2 rw2ea[32];
#pragma unroll
    for (int k = 0; k < 32; ++k) { rw2ea[k].x = 0.f; rw2ea[k].y = 0.f; }
    f32x2 eab2; eab2.x = 0.f; eab2.y = 0.f;
#pragma unroll 1
    for (int jc = 0; jc < 4; ++jc) {
        f32x2 ea[32];
#pragma unroll
        for (int i = 0; i < 32; ++i) {
            int j = 32 * jc + i;
            ea[i].x = ldw<BF16>(er_w, (size_t)j * DD + d);
            ea[i].y = ldw<BF16>(ad_w, (size_t)j * DD + d);
            float b2j = ldw<BF16>(vu_b2, j);
            f32x2 bs; bs.x = b2j; bs.y = b2j;
            eab2 = pkfma(bs, ea[i], eab2);
        }
#pragma unroll
        for (int k = 0; k < 32; ++k) {
            const uint4* wp = (const uint4*)&sm.v2.w2s[W2ROW(32 * q + k) + 16 * jc];
            uint4 A = wp[0], B = wp[1], C = wp[2], Dv = wp[3];
            unsigned int W[16] = { A.x, A.y, A.z, A.w, B.x, B.y, B.z, B.w,
                                   C.x, C.y, C.z, C.w, Dv.x, Dv.y, Dv.z, Dv.w };
            f32x2 acc = rw2ea[k];
#pragma unroll
            for (int wd = 0; wd < 16; ++wd) {
                float wlo = bfu_lo(W[wd]), whi = bfu_hi(W[wd]);
                f32x2 s0; s0.x = wlo; s0.y = wlo;
                f32x2 s1; s1.x = whi; s1.y = whi;
                acc = pkfma(s0, ea[2 * wd], acc);
                acc = pkfma(s1, ea[2 * wd + 1], acc);
            }
            rw2ea[k] = acc;
        }
    }
    eab2.x += ldw<BF16>(er_b, d);
    eab2.y += ldw<BF16>(ad_b, d);
    __syncthreads();

    float rw1a[32], rw1b[32];
#pragma unroll
    for (int i = 0; i < 32; ++i) {
        rw1a[i] = ldw<BF16>(vu_w1, (size_t)(32 * q + i) * DD + d);
        rw1b[i] = ldw<BF16>(vu_w1, (size_t)(DD + 32 * q + i) * DD + d);
    }
    const float b1r = ldw<BF16>(vu_b1, d);

    for (int ii = 0; ii < 13; ++ii) {
        const int nrows = (ii == 12) ? 4 : 8;
        {
            int r = t >> 6, w = t & 63;
            if (r < nrows) {
                int row = sm.qrow[8 * ii + r];
                if (BF16) {
                    sm.u.pre.qe8[r][w] = ((const unsigned int*)emb)[((size_t)row << 6) + w];
                } else {
                    const float* ef = (const float*)emb + (((size_t)row) << 7) + 2 * w;
                    sm.u.pre.qe8[r][w] = packbf(ef[0], ef[1]);
                }
            }
        }
        __syncthreads();

        if (wv < nrows) {
            int m = l;
            int mc = (m < MM) ? m : (MM - 1);
            float a0 = 0.f, a1 = 0.f, a2 = 0.f, a3 = 0.f;
#pragma unroll
            for (int j = 0; j < 32; ++j) {
                uint2 kw = *(const uint2*)&sm.u.pre.key_w[mc * KROW + 2 * j];
                uint2 qw = *(const uint2*)&sm.u.pre.qe8[wv][2 * j];
                a0 = fmaf(bfu_lo(kw.x), bfu_lo(qw.x), a0);
                a1 = fmaf(bfu_hi(kw.x), bfu_hi(qw.x), a1);
                a2 = fmaf(bfu_lo(kw.y), bfu_lo(qw.y), a2);
                a3 = fmaf(bfu_hi(kw.y), bfu_hi(qw.y), a3);
            }
            float lg = (a0 + a1) + (a2 + a3);
            if (m >= MM) lg = -1e30f;
            float mx = lg;
#pragma unroll
            for (int o = 32; o > 0; o >>= 1) mx = fmaxf(mx, __shfl_xor(mx, o));
            float p = (m < MM) ? __expf(lg - mx) : 0.f;
            float sum = p;
#pragma unroll
            for (int o = 32; o > 0; o >>= 1) sum += __shfl_xor(sum, o);
            p = p / sum;
            float pn = __shfl_xor(p, 4);
            if ((m & 4) == 0)
                sm.v2.tab.wrow_p[8 * ii + wv][(m & 3) * 8 + (m >> 3)] = packbf(p, pn);
        }

        for (int sr = 0; sr < nrows; ++sr) {
            float p0 = 0.f, p1 = 0.f;
#pragma unroll
            for (int i = 0; i < 16; ++i) {
                unsigned int uw = sm.u.pre.qe8[sr][16 * q + i];
                p0 = fmaf(rw1b[2 * i],     bfu_lo(uw), p0);
                p1 = fmaf(rw1b[2 * i + 1], bfu_hi(uw), p1);
            }
            float qpv = qbf_add(p0 + p1);
            if (q == 0) sm.v2.tab.qp_all[8 * ii + sr][d] = f2bf_bits(qpv);
        }
        __syncthreads();
    }

    if (t < 64) {
        unsigned int uw = sm.u.pre.qe8[3][t];
        sm.qlast[2 * t]     = bfu_lo(uw);
        sm.qlast[2 * t + 1] = bfu_hi(uw);
    }
    f32x2 v2[7];
#pragma unroll
    for (int p = 0; p < 7; ++p) { v2[p].x = 0.f; v2[p].y = 0.f; }
    f32x2 wr2[7];
    {
        const uint4* wp = (const uint4*)&sm.v2.tab.wrow_p[0][q * 8];
        uint4 w0 = wp[0], w1 = wp[1];
        unsigned int ww[8] = { w0.x, w0.y, w0.z, w0.w, w1.x, w1.y, w1.z, w1.w };
#pragma unroll
        for (int p = 0; p < 7; ++p) { wr2[p].x = bfu_lo(ww[p]); wr2[p].y = bfu_hi(ww[p]); }
    }
    if (t < 152) sm.u.run.xread[t] = 0.f;
    __syncthreads();

    for (int s = 0; s < SS; ++s) {
        {
            float qpv = bf2f(sm.v2.tab.qp_all[s][d]);
            const float4* xp = (const float4*)&sm.u.run.xread[40 * q];
            f32x2 rw1a2_j;
            f32x2 acc2; acc2.x = 0.f; acc2.y = 0.f;
#pragma unroll
            for (int j = 0; j < 8; ++j) {
                float4 X = xp[j];
                f32x2 x01; x01.x = X.x; x01.y = X.y;
                f32x2 x23; x23.x = X.z; x23.y = X.w;
                rw1a2_j.x = rw1a[4 * j];     rw1a2_j.y = rw1a[4 * j + 1];
                acc2 = pkfma(rw1a2_j, x01, acc2);
                rw1a2_j.x = rw1a[4 * j + 2]; rw1a2_j.y = rw1a[4 * j + 3];
                acc2 = pkfma(rw1a2_j, x23, acc2);
            }
            float acc = qbf_add(acc2.x + acc2.y);
            float hh = fast_tanh(acc + qpv + b1r);
            if (q == 0) {
                f32x2 hd; hd.x = hh; hd.y = hh;
                *(f32x2*)&sm.u.run.xhdup[2 * d + 8 * ((2 * d) >> 5)] = hd;
            }
        }
        __syncthreads();

        {
            f32x2 acc2; acc2.x = 0.f; acc2.y = 0.f;
#pragma unroll
            for (int blk = 0; blk < 2; ++blk) {
                const float4* xp = (const float4*)&sm.u.run.xhdup[80 * q + 40 * blk];
#pragma unroll
                for (int j = 0; j < 8; ++j) {
                    float4 X = xp[j];
                    f32x2 s0; s0.x = X.x; s0.y = X.y;
                    f32x2 s1; s1.x = X.z; s1.y = X.w;
                    int k = 16 * blk + 2 * j;
                    acc2 = pkfma(rw2ea[k], s0, acc2);
                    acc2 = pkfma(rw2ea[k + 1], s1, acc2);
                }
            }
            float ae = qbf_add(acc2.x);
            float aa = qbf_add(acc2.y);
            float e = fast_sigmoid(ae + eab2.x);
            float a = fast_tanh(aa + eab2.y);
            f32x2 me; me.x = -e; me.y = -e;
            f32x2 av; av.x = a;  av.y = a;
#pragma unroll
            for (int p = 0; p < 7; ++p)
                v2[p] = pkfma(wr2[p], pkfma(me, v2[p], av), v2[p]);
            if (s + 1 < SS) {
                const uint4* wp = (const uint4*)&sm.v2.tab.wrow_p[s + 1][q * 8];
                uint4 w0 = wp[0], w1 = wp[1];
                unsigned int ww[8] = { w0.x, w0.y, w0.z, w0.w, w1.x, w1.y, w1.z, w1.w };
#pragma unroll
                for (int p = 0; p < 7; ++p) { wr2[p].x = bfu_lo(ww[p]); wr2[p].y = bfu_hi(ww[p]); }
            }
            f32x2 racc; racc.x = 0.f; racc.y = 0.f;
#pragma unroll
            for (int p = 0; p < 7; ++p)
                racc = pkfma(wr2[p], v2[p], racc);
            float rr = qbf_add(racc.x + racc.y);
            if (q == 0) sm.u.run.xread[d + 8 * (d >> 5)] = rr;
        }
        __syncthreads();
    }

    float acc = 0.f;
    {
        const float4* xp = (const float4*)&sm.u.run.xread[40 * q];
        const float4* qp4 = (const float4*)&sm.qlast[32 * q];
#pragma unroll
        for (int j = 0; j < 8; ++j) {
            float4 xv = xp[j];
            float4 qv = qp4[j];
            int k = 32 * q + 4 * j;
            acc = fmaf(ldw<BF16>(out_w1, (size_t)k * DD + d),       xv.x, acc);
            acc = fmaf(ldw<BF16>(out_w1, (size_t)(k + 1) * DD + d), xv.y, acc);
            acc = fmaf(ldw<BF16>(out_w1, (size_t)(k + 2) * DD + d), xv.z, acc);
            acc = fmaf(ldw<BF16>(out_w1, (size_t)(k + 3) * DD + d), xv.w, acc);
            acc = fmaf(ldw<BF16>(out_w1, (size_t)(DD + k) * DD + d),     qv.x, acc);
            acc = fmaf(ldw<BF16>(out_w1, (size_t)(DD + k + 1) * DD + d), qv.y, acc);
            acc = fmaf(ldw<BF16>(out_w1, (size_t)(DD + k + 2) * DD + d), qv.z, acc);
            acc = fmaf(ldw<BF16>(out_w1, (size_t)(DD + k + 3) * DD + d), qv.w, acc);
        }
    }
    acc = qbf_add(acc);
    float h1 = fmaxf(acc + ldw<BF16>(out_b1, d), 0.f);
    if (q == 0) sm.u.run.h1f[d] = h1;
    __syncthreads();

    if (t < 64) {
        float xs = fmaf(sm.u.run.h1f[t], ldw<BF16>(out_w2, t),
                        sm.u.run.h1f[64 + t] * ldw<BF16>(out_w2, 64 + t));
#pragma unroll
        for (int o = 32; o > 0; o >>= 1) xs += __shfl_xor(xs, o);
        if (t == 0) {
            float pred = fast_sigmoid(xs + ldw<BF16>(out_b2, 0));
            if (BF16) ((unsigned short*)outp)[b] = f2bf_bits(pred);
            else      ((float*)outp)[b] = pred;
        }
    }
}

__global__ __launch_bounds__(512) void DKVMN_78546361909953_kernel(
    const int* __restrict__ qseq,
    const void* emb, const void* key,
    const void* vu_w1, const void* vu_b1, const void* vu_w2, const void* vu_b2,
    const void* er_w, const void* er_b, const void* ad_w, const void* ad_b,
    const void* out_w1, const void* out_b1, const void* out_w2, const void* out_b2,
    void* outp)
{
    __shared__ SmemM sm;
    if (detect_bf16(emb))
        mono_impl<true>(qseq, emb, key, vu_w1, vu_b1, vu_w2, vu_b2,
                        er_w, er_b, ad_w, ad_b, out_w1, out_b1, out_w2, out_b2, outp, sm);
    else
        mono_impl<false>(qseq, emb, key, vu_w1, vu_b1, vu_w2, vu_b2,
                         er_w, er_b, ad_w, ad_b, out_w1, out_b1, out_w2, out_b2, outp, sm);
}

extern "C" void kernel_launch(void* const* d_in, const int* in_sizes, int n_in,
                              void* d_out, int out_size, void* d_ws, size_t ws_size,
                              hipStream_t stream) {
    const int* qseq = (const int*)d_in[0];
    // d_in[1] = answer_seq: unused by the reference
    if (ws_size >= (size_t)WS_NEED) {
        DKVMN_78546361909953_pre<<<dim3(BB + 1, 2), 512, 0, stream>>>(
            qseq, d_in[2], d_in[3], d_in[4],
            d_in[6], d_in[7], d_in[8], d_in[9], d_in[10], d_in[11], d_ws);
        DKVMN_78546361909953_scan<<<BB, 512, 0, stream>>>(
            qseq, d_in[2], d_in[4], d_in[5],
            d_in[12], d_in[13], d_in[14], d_in[15], d_ws, d_out);
    } else {
        DKVMN_78546361909953_kernel<<<BB, 512, 0, stream>>>(
            qseq, d_in[2], d_in[3], d_in[4], d_in[5], d_in[6], d_in[7],
            d_in[8], d_in[9], d_in[10], d_in[11],
            d_in[12], d_in[13], d_in[14], d_in[15], d_out);
    }
}